// Round 2
// 3607.236 us; speedup vs baseline: 1.1486x; 1.1486x over previous
//
#include <hip/hip_runtime.h>
#include <cstdint>
#include <cstddef>

// ---- problem constants ----
#define BT   2048      // B*T
#define TT   1024      // T
#define CC   768       // C
#define HH   12        // heads
#define LL   12        // layers
#define VV   50257     // vocab
#define VPAD 50304     // vocab padded to multiple of 128

typedef __attribute__((ext_vector_type(8))) short short8;   // 8 bf16 (4 VGPRs)
typedef __attribute__((ext_vector_type(4))) short short4v;  // 4 bf16
typedef __attribute__((ext_vector_type(4))) float float4v;  // MFMA C/D, also f32x4 loads

// f32 -> bf16 round-to-nearest-even (finite inputs only)
__device__ __forceinline__ short f2bf(float f) {
  union { float f; uint32_t u; } v; v.f = f;
  uint32_t r = v.u + 0x7FFFu + ((v.u >> 16) & 1u);
  return (short)(r >> 16);
}

// async global->LDS, 16B per lane; lds base must be wave-uniform (dest = base + lane*16)
__device__ __forceinline__ void gl2lds16(const short* g, const short* lds_base) {
  __builtin_amdgcn_global_load_lds(
      (const __attribute__((address_space(1))) void*)g,
      (__attribute__((address_space(3))) void*)lds_base, 16, 0, 0);
}

// ---------------- cast wte -> bf16 head matrix (padded rows zeroed), vectorized ----------------
__global__ __launch_bounds__(256) void cast_pad_kernel(const float* __restrict__ in,
                                                       short* __restrict__ out,
                                                       long n_in, long n_out) {
  long i = ((long)blockIdx.x * 256 + threadIdx.x) * 4;
  if (i >= n_out) return;
  short4v o;
  if (i + 4 <= n_in) {
    float4v f = *(const float4v*)(in + i);
    o[0] = f2bf(f[0]); o[1] = f2bf(f[1]); o[2] = f2bf(f[2]); o[3] = f2bf(f[3]);
  } else {
#pragma unroll
    for (int j = 0; j < 4; ++j) {
      long k = i + j;
      o[j] = (k < n_in) ? f2bf(in[k]) : (short)0;
    }
  }
  *(short4v*)(out + i) = o;
}

// ---------------- tiled transpose + cast: in f32 [K,N] -> out bf16 [N,K] ----------------
// blockIdx.z = layer (strides ils/ols); z=1 + offset pointers for the per-layer fallback
__global__ __launch_bounds__(256) void transpose_cast_kernel(const float* __restrict__ in,
                                                             short* __restrict__ out,
                                                             int K, int N,
                                                             long ils, long ols) {
  in  += (size_t)blockIdx.z * ils;
  out += (size_t)blockIdx.z * ols;
  __shared__ float tile[32][33];
  int n0 = blockIdx.x * 32, k0 = blockIdx.y * 32;
  int c = threadIdx.x & 31, r = threadIdx.x >> 5;  // r: 0..7
#pragma unroll
  for (int rr = 0; rr < 32; rr += 8)
    tile[rr + r][c] = in[(size_t)(k0 + rr + r) * N + n0 + c];
  __syncthreads();
#pragma unroll
  for (int rr = 0; rr < 32; rr += 8)
    out[(size_t)(n0 + rr + r) * K + k0 + c] = f2bf(tile[c][rr + r]);
}

// ---------------- embedding: x = wte[idx] + wpe[t] ----------------
__global__ __launch_bounds__(256) void embed_kernel(const int* __restrict__ idx,
                                                    const float* __restrict__ wte,
                                                    const float* __restrict__ wpe,
                                                    float* __restrict__ x) {
  int row = blockIdx.x, tid = threadIdx.x;
  int tok = idx[row];
  int t = row & (TT - 1);
#pragma unroll
  for (int kk = 0; kk < 3; ++kk) {
    int c = tid + kk * 256;
    x[(size_t)row * CC + c] = wte[(size_t)tok * CC + c] + wpe[(size_t)t * CC + c];
  }
}

// ---------------- LayerNorm (f32 in) -> bf16 out ----------------
__global__ __launch_bounds__(256) void ln_kernel(const float* __restrict__ x,
                                                 const float* __restrict__ g,
                                                 const float* __restrict__ bta,
                                                 short* __restrict__ out) {
  int row = blockIdx.x, tid = threadIdx.x;
  const float* xr = x + (size_t)row * CC;
  float v0 = xr[tid], v1 = xr[tid + 256], v2 = xr[tid + 512];
  float s = v0 + v1 + v2;
#pragma unroll
  for (int off = 32; off >= 1; off >>= 1) s += __shfl_xor(s, off, 64);
  __shared__ float red[8];
  int wid = tid >> 6;
  if ((tid & 63) == 0) red[wid] = s;
  __syncthreads();
  float mean = (red[0] + red[1] + red[2] + red[3]) * (1.0f / CC);
  float d0 = v0 - mean, d1 = v1 - mean, d2 = v2 - mean;
  float q = d0 * d0 + d1 * d1 + d2 * d2;
#pragma unroll
  for (int off = 32; off >= 1; off >>= 1) q += __shfl_xor(q, off, 64);
  if ((tid & 63) == 0) red[4 + wid] = q;
  __syncthreads();
  float var = (red[4] + red[5] + red[6] + red[7]) * (1.0f / CC);
  float rstd = rsqrtf(var + 1e-5f);
  out[(size_t)row * CC + tid]       = f2bf(d0 * rstd * g[tid]       + bta[tid]);
  out[(size_t)row * CC + tid + 256] = f2bf(d1 * rstd * g[tid + 256] + bta[tid + 256]);
  out[(size_t)row * CC + tid + 512] = f2bf(d2 * rstd * g[tid + 512] + bta[tid + 512]);
}

// ---------------- GEMM-NT 128x128: C[M,N] = A[M,K](bf16) * Bt[N,K](bf16)^T ----------------
// MODE 0: out_bf16 = C + bias            (qkv)
// MODE 1: resf    += C + bias  (f32, in-place residual)
// MODE 2: out_bf16 = gelu(C + bias)      (fc)
// MODE 3: out_f32  = C, cols masked to Nvalid (head, no bias), nontemporal stores
// SWZ 1: 1-D launch; per-XCD contiguous chunks, N-chunk-major with all 16 M-blocks
//        adjacent so a B-panel tile is fetched once per XCD L2 (head GEMM only).
template <int MODE, int SWZ = 0>
__global__ __launch_bounds__(256) void gemm_nt(const short* __restrict__ A,
                                               const short* __restrict__ Bt,
                                               const float* __restrict__ bias,
                                               float* __restrict__ resf,
                                               short* __restrict__ outb,
                                               float* __restrict__ outf,
                                               int K, int ldo, int Nvalid) {
  __shared__ __align__(16) short As[128 * 32];
  __shared__ __align__(16) short Bs[128 * 32];
  const int tid = threadIdx.x;
  const int w = tid >> 6, lane = tid & 63, quad = lane >> 4, l16 = lane & 15;
  const int wr = w & 1, wc = w >> 1;

  int bx, by;
  if (SWZ) {
    // grid is 1-D, gridDim.x % 8 == 0; consecutive ids round-robin XCDs, so
    // (id&7)*per + id>>3 gives each XCD a contiguous chunk; within the chunk
    // decompose M-inner (16 M-blocks share one B column tile in that XCD's L2).
    unsigned per = gridDim.x >> 3;
    unsigned g = (blockIdx.x & 7u) * per + (blockIdx.x >> 3);
    by = g & (BT / 128 - 1);   // 16 M-blocks, M inner
    bx = g >> 4;
  } else {
    bx = blockIdx.x; by = blockIdx.y;
  }
  const int m0 = by * 128, n0 = bx * 128;

  float4v acc[4][4];
#pragma unroll
  for (int i = 0; i < 4; ++i)
#pragma unroll
    for (int j = 0; j < 4; ++j) acc[i][j] = float4v{0.f, 0.f, 0.f, 0.f};

  const int r0 = tid >> 2;          // staging row 0..63
  const int c0 = (tid & 3) * 8;     // staging col chunk
  const short* ga0 = A  + (size_t)(m0 + r0) * K + c0;
  const short* ga1 = A  + (size_t)(m0 + 64 + r0) * K + c0;
  const short* gb0 = Bt + (size_t)(n0 + r0) * K + c0;
  const short* gb1 = Bt + (size_t)(n0 + 64 + r0) * K + c0;
  const short* lA0 = As + w * 512;
  const short* lA1 = As + 2048 + w * 512;
  const short* lB0 = Bs + w * 512;
  const short* lB1 = Bs + 2048 + w * 512;

  const int kTiles = K >> 5;
  for (int kt = 0; kt < kTiles; ++kt) {
    const int ko = kt * 32;
    __syncthreads();
    gl2lds16(ga0 + ko, lA0);
    gl2lds16(ga1 + ko, lA1);
    gl2lds16(gb0 + ko, lB0);
    gl2lds16(gb1 + ko, lB1);
    __syncthreads();
    short8 af[4], bfr[4];
#pragma unroll
    for (int t = 0; t < 4; ++t) {
      af[t]  = *(const short8*)&As[(wr * 64 + t * 16 + l16) * 32 + quad * 8];
      bfr[t] = *(const short8*)&Bs[(wc * 64 + t * 16 + l16) * 32 + quad * 8];
    }
#pragma unroll
    for (int i = 0; i < 4; ++i)
#pragma unroll
      for (int j = 0; j < 4; ++j)
        acc[i][j] = __builtin_amdgcn_mfma_f32_16x16x32_bf16(af[i], bfr[j], acc[i][j], 0, 0, 0);
  }

  // epilogue: C/D layout col = l16, row = quad*4 + r
#pragma unroll
  for (int i = 0; i < 4; ++i) {
#pragma unroll
    for (int j = 0; j < 4; ++j) {
#pragma unroll
      for (int r = 0; r < 4; ++r) {
        int gm = m0 + wr * 64 + i * 16 + quad * 4 + r;
        int gn = n0 + wc * 64 + j * 16 + l16;
        float v = acc[i][j][r];
        if (MODE == 0) {
          outb[(size_t)gm * ldo + gn] = f2bf(v + bias[gn]);
        } else if (MODE == 1) {
          size_t o = (size_t)gm * ldo + gn;
          resf[o] = resf[o] + v + bias[gn];
        } else if (MODE == 2) {
          float t = v + bias[gn];
          float gl = 0.5f * t * (1.0f + erff(t * 0.70710678118654752f));
          outb[(size_t)gm * ldo + gn] = f2bf(gl);
        } else {
          // write-once logits: nontemporal so the 412 MB stream doesn't evict B from L2/L3
          if (gn < Nvalid) __builtin_nontemporal_store(v, outf + (size_t)gm * ldo + gn);
        }
      }
    }
  }
}

// ---------------- GEMM-NT 64x64 tile: for N=768 GEMMs (proj / fc-proj) ----------------
// Same math/K-order as the 128 version (bitwise-identical sums), 4x the blocks:
// grid (N/64, M/64) = 384 blocks instead of 96 -> ~4.5 resident blocks/CU.
template <int MODE>
__global__ __launch_bounds__(256) void gemm_nt64(const short* __restrict__ A,
                                                 const short* __restrict__ Bt,
                                                 const float* __restrict__ bias,
                                                 float* __restrict__ resf,
                                                 short* __restrict__ outb,
                                                 int K, int ldo) {
  __shared__ __align__(16) short As[64 * 32];
  __shared__ __align__(16) short Bs[64 * 32];
  const int tid = threadIdx.x;
  const int w = tid >> 6, lane = tid & 63, quad = lane >> 4, l16 = lane & 15;
  const int wr = w & 1, wc = w >> 1;
  const int m0 = blockIdx.y * 64, n0 = blockIdx.x * 64;

  float4v acc[2][2];
#pragma unroll
  for (int i = 0; i < 2; ++i)
#pragma unroll
    for (int j = 0; j < 2; ++j) acc[i][j] = float4v{0.f, 0.f, 0.f, 0.f};

  const int r0 = tid >> 2;          // staging row 0..63
  const int c0 = (tid & 3) * 8;
  const short* ga = A  + (size_t)(m0 + r0) * K + c0;
  const short* gb = Bt + (size_t)(n0 + r0) * K + c0;
  const short* lA = As + w * 512;   // wave w stages rows [w*16, w*16+16)
  const short* lB = Bs + w * 512;

  const int kTiles = K >> 5;
  for (int kt = 0; kt < kTiles; ++kt) {
    const int ko = kt * 32;
    __syncthreads();
    gl2lds16(ga + ko, lA);
    gl2lds16(gb + ko, lB);
    __syncthreads();
    short8 af[2], bfr[2];
#pragma unroll
    for (int t = 0; t < 2; ++t) {
      af[t]  = *(const short8*)&As[(wr * 32 + t * 16 + l16) * 32 + quad * 8];
      bfr[t] = *(const short8*)&Bs[(wc * 32 + t * 16 + l16) * 32 + quad * 8];
    }
#pragma unroll
    for (int i = 0; i < 2; ++i)
#pragma unroll
      for (int j = 0; j < 2; ++j)
        acc[i][j] = __builtin_amdgcn_mfma_f32_16x16x32_bf16(af[i], bfr[j], acc[i][j], 0, 0, 0);
  }

#pragma unroll
  for (int i = 0; i < 2; ++i) {
#pragma unroll
    for (int j = 0; j < 2; ++j) {
#pragma unroll
      for (int r = 0; r < 4; ++r) {
        int gm = m0 + wr * 32 + i * 16 + quad * 4 + r;
        int gn = n0 + wc * 32 + j * 16 + l16;
        float v = acc[i][j][r];
        if (MODE == 0) {
          outb[(size_t)gm * ldo + gn] = f2bf(v + bias[gn]);
        } else if (MODE == 1) {
          size_t o = (size_t)gm * ldo + gn;
          resf[o] = resf[o] + v + bias[gn];
        } else if (MODE == 2) {
          float t = v + bias[gn];
          float gl = 0.5f * t * (1.0f + erff(t * 0.70710678118654752f));
          outb[(size_t)gm * ldo + gn] = f2bf(gl);
        }
      }
    }
  }
}

// ---------------- flash attention: qkv bf16 [B*T, H*192] -> o bf16 [B*T, C] ----------------
__global__ __launch_bounds__(256) void attn_kernel(const short* __restrict__ qkv,
                                                   short* __restrict__ o) {
  __shared__ __align__(16) short Vt[64 * 32];      // V^T tile: [d][s]
  __shared__ __align__(16) short Pl[4][16 * 32];   // per-wave P tile
  const int tid = threadIdx.x;
  const int w = tid >> 6, lane = tid & 63, quad = lane >> 4, l16 = lane & 15;
  const int b = blockIdx.z, h = blockIdx.y, q0 = blockIdx.x * 64;
  const size_t rs = 3 * CC;  // 2304
  const size_t base = (size_t)b * TT * rs + (size_t)h * 192;

  short8 qa[2];
  {
    int t = q0 + w * 16 + l16;
    const short* qp = qkv + base + (size_t)t * rs + quad * 8;
    qa[0] = *(const short8*)(qp);
    qa[1] = *(const short8*)(qp + 32);
  }
  float4v oacc[4];
#pragma unroll
  for (int i = 0; i < 4; ++i) oacc[i] = float4v{0.f, 0.f, 0.f, 0.f};
  float mrun[4] = {-1e30f, -1e30f, -1e30f, -1e30f};
  float lrun[4] = {0.f, 0.f, 0.f, 0.f};

  const int nst = q0 / 32 + 2;
  for (int st = 0; st < nst; ++st) {
    const int s0 = st * 32;
    __syncthreads();
    {   // stage V tile transposed: Vt[d][s]
      int sl = tid >> 3;          // 0..31
      int d0 = (tid & 7) * 8;
      const short* vp = qkv + base + (size_t)(s0 + sl) * rs + 128 + d0;
      short8 v8 = *(const short8*)vp;
#pragma unroll
      for (int j = 0; j < 8; ++j) Vt[(d0 + j) * 32 + sl] = v8[j];
    }
    __syncthreads();

    float4v S[2];
#pragma unroll
    for (int nt = 0; nt < 2; ++nt) {
      int s = s0 + nt * 16 + l16;
      const short* kp = qkv + base + (size_t)s * rs + 64 + quad * 8;
      short8 kb0 = *(const short8*)kp;
      short8 kb1 = *(const short8*)(kp + 32);
      float4v z = float4v{0.f, 0.f, 0.f, 0.f};
      z = __builtin_amdgcn_mfma_f32_16x16x32_bf16(qa[0], kb0, z, 0, 0, 0);
      z = __builtin_amdgcn_mfma_f32_16x16x32_bf16(qa[1], kb1, z, 0, 0, 0);
      S[nt] = z;
    }

#pragma unroll
    for (int r = 0; r < 4; ++r) {
      int trow = q0 + w * 16 + quad * 4 + r;
      float s0v = (s0 + l16      <= trow) ? S[0][r] * 0.125f : -1e30f;
      float s1v = (s0 + 16 + l16 <= trow) ? S[1][r] * 0.125f : -1e30f;
      float tm = fmaxf(s0v, s1v);
#pragma unroll
      for (int off = 1; off < 16; off <<= 1) tm = fmaxf(tm, __shfl_xor(tm, off, 64));
      float mnew = fmaxf(mrun[r], tm);
      float alpha = __expf(mrun[r] - mnew);
      mrun[r] = mnew;
      float p0 = __expf(s0v - mnew);
      float p1 = __expf(s1v - mnew);
      float rsum = p0 + p1;
#pragma unroll
      for (int off = 1; off < 16; off <<= 1) rsum += __shfl_xor(rsum, off, 64);
      lrun[r] = lrun[r] * alpha + rsum;
#pragma unroll
      for (int dc = 0; dc < 4; ++dc) oacc[dc][r] *= alpha;
      Pl[w][(quad * 4 + r) * 32 + l16]      = f2bf(p0);
      Pl[w][(quad * 4 + r) * 32 + 16 + l16] = f2bf(p1);
    }
    __syncthreads();

    short8 pa = *(const short8*)&Pl[w][l16 * 32 + quad * 8];
#pragma unroll
    for (int dc = 0; dc < 4; ++dc) {
      short8 vb = *(const short8*)&Vt[(dc * 16 + l16) * 32 + quad * 8];
      oacc[dc] = __builtin_amdgcn_mfma_f32_16x16x32_bf16(pa, vb, oacc[dc], 0, 0, 0);
    }
  }

#pragma unroll
  for (int dc = 0; dc < 4; ++dc)
#pragma unroll
    for (int r = 0; r < 4; ++r) {
      int t = q0 + w * 16 + quad * 4 + r;
      float val = oacc[dc][r] / lrun[r];
      o[(size_t)(b * TT + t) * CC + h * 64 + dc * 16 + l16] = f2bf(val);
    }
}

// ---------------- host ----------------
extern "C" void kernel_launch(void* const* d_in, const int* in_sizes, int n_in,
                              void* d_out, int out_size, void* d_ws, size_t ws_size,
                              hipStream_t stream) {
  const int*   idx   = (const int*)d_in[0];
  const float* wte   = (const float*)d_in[1];
  const float* wpe   = (const float*)d_in[2];
  const float* ln1g  = (const float*)d_in[3];
  const float* ln1b  = (const float*)d_in[4];
  const float* attnw = (const float*)d_in[5];
  const float* attnb = (const float*)d_in[6];
  const float* projw = (const float*)d_in[7];
  const float* projb = (const float*)d_in[8];
  const float* ln2g  = (const float*)d_in[9];
  const float* ln2b  = (const float*)d_in[10];
  const float* fcw   = (const float*)d_in[11];
  const float* fcb   = (const float*)d_in[12];
  const float* fpw   = (const float*)d_in[13];
  const float* fpb   = (const float*)d_in[14];
  const float* lnfg  = (const float*)d_in[15];
  const float* lnfb  = (const float*)d_in[16];
  float* out = (float*)d_out;

  char* p = (char*)d_ws;
  auto alloc = [&](size_t bytes) {
    char* r = p;
    p += (bytes + 255) & ~(size_t)255;
    return r;
  };

  const size_t SZ_ATTN = (size_t)3 * CC * CC * 2;
  const size_t SZ_PROJ = (size_t)CC * CC * 2;
  const size_t SZ_FC   = (size_t)4 * CC * CC * 2;
  const size_t SZ_FP   = (size_t)4 * CC * CC * 2;
  // batched path needs ~282 MB total; gate with margin, exact fallback otherwise
  const bool big = ws_size >= (size_t)300 * 1024 * 1024;
  const int wmul = big ? LL : 1;

  short* wt_head = (short*)alloc((size_t)VPAD * CC * 2);   // 77.3 MB
  short* wt_attn = (short*)alloc(SZ_ATTN * wmul);
  short* wt_proj = (short*)alloc(SZ_PROJ * wmul);
  short* wt_fc   = (short*)alloc(SZ_FC * wmul);
  short* wt_fp   = (short*)alloc(SZ_FP * wmul);
  float* x       = (float*)alloc((size_t)BT * CC * 4);     // f32 residual stream
  short* hbuf    = (short*)alloc((size_t)BT * CC * 2);     // LN output (bf16)
  short* obuf    = (short*)alloc((size_t)BT * CC * 2);     // attention output (bf16)
  short* qkvb    = (short*)alloc((size_t)BT * 3 * CC * 2); // qkv (bf16)
  short* fcout   = (short*)alloc((size_t)BT * 4 * CC * 2); // gelu(fc) (bf16)

  cast_pad_kernel<<<dim3(((long)VPAD * CC) / 1024), 256, 0, stream>>>(
      wte, wt_head, (long)VV * CC, (long)VPAD * CC);
  embed_kernel<<<dim3(BT), 256, 0, stream>>>(idx, wte, wpe, x);

  if (big) {
    // all 12 layers' weight transposes in 4 launches (z = layer)
    transpose_cast_kernel<<<dim3(2304 / 32, 768 / 32, LL), 256, 0, stream>>>(
        attnw, wt_attn, CC, 3 * CC, (long)CC * 3 * CC, (long)3 * CC * CC);
    transpose_cast_kernel<<<dim3(768 / 32, 768 / 32, LL), 256, 0, stream>>>(
        projw, wt_proj, CC, CC, (long)CC * CC, (long)CC * CC);
    transpose_cast_kernel<<<dim3(3072 / 32, 768 / 32, LL), 256, 0, stream>>>(
        fcw, wt_fc, CC, 4 * CC, (long)CC * 4 * CC, (long)4 * CC * CC);
    transpose_cast_kernel<<<dim3(768 / 32, 3072 / 32, LL), 256, 0, stream>>>(
        fpw, wt_fp, 4 * CC, CC, (long)4 * CC * CC, (long)4 * CC * CC);
  }

  for (int l = 0; l < LL; ++l) {
    const short* wa = wt_attn + (big ? (size_t)l * 3 * CC * CC : 0);
    const short* wp = wt_proj + (big ? (size_t)l * CC * CC : 0);
    const short* wf = wt_fc   + (big ? (size_t)l * 4 * CC * CC : 0);
    const short* wq = wt_fp   + (big ? (size_t)l * 4 * CC * CC : 0);

    if (!big) {
      transpose_cast_kernel<<<dim3(2304 / 32, 768 / 32, 1), 256, 0, stream>>>(
          attnw + (size_t)l * CC * 3 * CC, wt_attn, CC, 3 * CC, 0, 0);
      transpose_cast_kernel<<<dim3(768 / 32, 768 / 32, 1), 256, 0, stream>>>(
          projw + (size_t)l * CC * CC, wt_proj, CC, CC, 0, 0);
      transpose_cast_kernel<<<dim3(3072 / 32, 768 / 32, 1), 256, 0, stream>>>(
          fcw + (size_t)l * CC * 4 * CC, wt_fc, CC, 4 * CC, 0, 0);
      transpose_cast_kernel<<<dim3(768 / 32, 3072 / 32, 1), 256, 0, stream>>>(
          fpw + (size_t)l * 4 * CC * CC, wt_fp, 4 * CC, CC, 0, 0);
    }

    ln_kernel<<<dim3(BT), 256, 0, stream>>>(x, ln1g + l * CC, ln1b + l * CC, hbuf);
    gemm_nt<0><<<dim3(18, 16), 256, 0, stream>>>(
        hbuf, wa, attnb + (size_t)l * 3 * CC, nullptr, qkvb, nullptr, CC, 3 * CC, 3 * CC);
    attn_kernel<<<dim3(TT / 64, HH, 2), 256, 0, stream>>>(qkvb, obuf);
    gemm_nt64<1><<<dim3(12, 32), 256, 0, stream>>>(
        obuf, wp, projb + (size_t)l * CC, x, nullptr, CC, CC);
    ln_kernel<<<dim3(BT), 256, 0, stream>>>(x, ln2g + l * CC, ln2b + l * CC, hbuf);
    gemm_nt<2><<<dim3(24, 16), 256, 0, stream>>>(
        hbuf, wf, fcb + (size_t)l * 4 * CC, nullptr, fcout, nullptr, CC, 4 * CC, 4 * CC);
    gemm_nt64<1><<<dim3(12, 32), 256, 0, stream>>>(
        fcout, wq, fpb + (size_t)l * CC, x, nullptr, 4 * CC, CC);
  }

  ln_kernel<<<dim3(BT), 256, 0, stream>>>(x, lnfg, lnfb, hbuf);
  // head: 1-D swizzled launch (6288 blocks, %8==0 -> bijective XCD chunks)
  gemm_nt<3, 1><<<dim3((VPAD / 128) * 16), 256, 0, stream>>>(
      hbuf, wt_head, nullptr, nullptr, nullptr, out, CC, VV, VV);
}

// Round 3
// 3445.892 us; speedup vs baseline: 1.2024x; 1.0468x over previous
//
#include <hip/hip_runtime.h>
#include <cstdint>
#include <cstddef>

// ---- problem constants ----
#define BT   2048      // B*T
#define TT   1024      // T
#define CC   768       // C
#define HH   12        // heads
#define LL   12        // layers
#define VV   50257     // vocab
#define VPAD 50304     // vocab padded to multiple of 128

typedef __attribute__((ext_vector_type(8))) short short8;   // 8 bf16 (4 VGPRs)
typedef __attribute__((ext_vector_type(4))) short short4v;  // 4 bf16
typedef __attribute__((ext_vector_type(4))) float float4v;  // MFMA C/D, also f32x4 loads

// f32 -> bf16 round-to-nearest-even (finite inputs only)
__device__ __forceinline__ short f2bf(float f) {
  union { float f; uint32_t u; } v; v.f = f;
  uint32_t r = v.u + 0x7FFFu + ((v.u >> 16) & 1u);
  return (short)(r >> 16);
}

// async global->LDS, 16B per lane; lds base must be wave-uniform (dest = base + lane*16)
__device__ __forceinline__ void gl2lds16(const short* g, const short* lds_base) {
  __builtin_amdgcn_global_load_lds(
      (const __attribute__((address_space(1))) void*)g,
      (__attribute__((address_space(3))) void*)lds_base, 16, 0, 0);
}

// ---------------- cast wte -> bf16 head matrix (padded rows zeroed), vectorized ----------------
__global__ __launch_bounds__(256) void cast_pad_kernel(const float* __restrict__ in,
                                                       short* __restrict__ out,
                                                       long n_in, long n_out) {
  long i = ((long)blockIdx.x * 256 + threadIdx.x) * 4;
  if (i >= n_out) return;
  short4v o;
  if (i + 4 <= n_in) {
    float4v f = *(const float4v*)(in + i);
    o[0] = f2bf(f[0]); o[1] = f2bf(f[1]); o[2] = f2bf(f[2]); o[3] = f2bf(f[3]);
  } else {
#pragma unroll
    for (int j = 0; j < 4; ++j) {
      long k = i + j;
      o[j] = (k < n_in) ? f2bf(in[k]) : (short)0;
    }
  }
  *(short4v*)(out + i) = o;
}

// ---------------- tiled transpose + cast: in f32 [K,N] -> out bf16 [N,K] ----------------
// blockIdx.z = layer (strides ils/ols); z=1 + offset pointers for the per-layer fallback
__global__ __launch_bounds__(256) void transpose_cast_kernel(const float* __restrict__ in,
                                                             short* __restrict__ out,
                                                             int K, int N,
                                                             long ils, long ols) {
  in  += (size_t)blockIdx.z * ils;
  out += (size_t)blockIdx.z * ols;
  __shared__ float tile[32][33];
  int n0 = blockIdx.x * 32, k0 = blockIdx.y * 32;
  int c = threadIdx.x & 31, r = threadIdx.x >> 5;  // r: 0..7
#pragma unroll
  for (int rr = 0; rr < 32; rr += 8)
    tile[rr + r][c] = in[(size_t)(k0 + rr + r) * N + n0 + c];
  __syncthreads();
#pragma unroll
  for (int rr = 0; rr < 32; rr += 8)
    out[(size_t)(n0 + rr + r) * K + k0 + c] = f2bf(tile[c][rr + r]);
}

// ---------------- embedding: x = wte[idx] + wpe[t] ----------------
__global__ __launch_bounds__(256) void embed_kernel(const int* __restrict__ idx,
                                                    const float* __restrict__ wte,
                                                    const float* __restrict__ wpe,
                                                    float* __restrict__ x) {
  int row = blockIdx.x, tid = threadIdx.x;
  int tok = idx[row];
  int t = row & (TT - 1);
#pragma unroll
  for (int kk = 0; kk < 3; ++kk) {
    int c = tid + kk * 256;
    x[(size_t)row * CC + c] = wte[(size_t)tok * CC + c] + wpe[(size_t)t * CC + c];
  }
}

// ---------------- LayerNorm (f32 in) -> bf16 out ----------------
__global__ __launch_bounds__(256) void ln_kernel(const float* __restrict__ x,
                                                 const float* __restrict__ g,
                                                 const float* __restrict__ bta,
                                                 short* __restrict__ out) {
  int row = blockIdx.x, tid = threadIdx.x;
  const float* xr = x + (size_t)row * CC;
  float v0 = xr[tid], v1 = xr[tid + 256], v2 = xr[tid + 512];
  float s = v0 + v1 + v2;
#pragma unroll
  for (int off = 32; off >= 1; off >>= 1) s += __shfl_xor(s, off, 64);
  __shared__ float red[8];
  int wid = tid >> 6;
  if ((tid & 63) == 0) red[wid] = s;
  __syncthreads();
  float mean = (red[0] + red[1] + red[2] + red[3]) * (1.0f / CC);
  float d0 = v0 - mean, d1 = v1 - mean, d2 = v2 - mean;
  float q = d0 * d0 + d1 * d1 + d2 * d2;
#pragma unroll
  for (int off = 32; off >= 1; off >>= 1) q += __shfl_xor(q, off, 64);
  if ((tid & 63) == 0) red[4 + wid] = q;
  __syncthreads();
  float var = (red[4] + red[5] + red[6] + red[7]) * (1.0f / CC);
  float rstd = rsqrtf(var + 1e-5f);
  out[(size_t)row * CC + tid]       = f2bf(d0 * rstd * g[tid]       + bta[tid]);
  out[(size_t)row * CC + tid + 256] = f2bf(d1 * rstd * g[tid + 256] + bta[tid + 256]);
  out[(size_t)row * CC + tid + 512] = f2bf(d2 * rstd * g[tid + 512] + bta[tid + 512]);
}

// ---------------- GEMM-NT 128x128: C[M,N] = A[M,K](bf16) * Bt[N,K](bf16)^T ----------------
// MODE 0: out_bf16 = C + bias            (qkv)
// MODE 1: resf    += C + bias  (f32, in-place residual)
// MODE 2: out_bf16 = gelu(C + bias)      (fc)
// MODE 3: out_f32  = C, cols masked to Nvalid (head, no bias)
//         plain stores: L2 merges the 64B quad-row segments into full lines
//         (round-2 counter-proof: nontemporal streamed partial lines -> WRITE
//          427->792 MB and dur 290->459 us; FETCH=89MB shows B-reuse survives
//          the write stream regardless, so NT buys nothing)
// SWZ 1: 1-D launch; per-XCD contiguous chunks, N-chunk-major with all 16 M-blocks
//        adjacent so a B-panel tile is fetched once per XCD L2 (head GEMM only).
//        (round-2 counter-proof: FETCH 650->89 MB)
template <int MODE, int SWZ = 0>
__global__ __launch_bounds__(256) void gemm_nt(const short* __restrict__ A,
                                               const short* __restrict__ Bt,
                                               const float* __restrict__ bias,
                                               float* __restrict__ resf,
                                               short* __restrict__ outb,
                                               float* __restrict__ outf,
                                               int K, int ldo, int Nvalid) {
  __shared__ __align__(16) short As[128 * 32];
  __shared__ __align__(16) short Bs[128 * 32];
  const int tid = threadIdx.x;
  const int w = tid >> 6, lane = tid & 63, quad = lane >> 4, l16 = lane & 15;
  const int wr = w & 1, wc = w >> 1;

  int bx, by;
  if (SWZ) {
    // grid is 1-D, gridDim.x % 8 == 0; consecutive ids round-robin XCDs, so
    // (id&7)*per + id>>3 gives each XCD a contiguous chunk; within the chunk
    // decompose M-inner (16 M-blocks share one B column tile in that XCD's L2).
    unsigned per = gridDim.x >> 3;
    unsigned g = (blockIdx.x & 7u) * per + (blockIdx.x >> 3);
    by = g & (BT / 128 - 1);   // 16 M-blocks, M inner
    bx = g >> 4;
  } else {
    bx = blockIdx.x; by = blockIdx.y;
  }
  const int m0 = by * 128, n0 = bx * 128;

  float4v acc[4][4];
#pragma unroll
  for (int i = 0; i < 4; ++i)
#pragma unroll
    for (int j = 0; j < 4; ++j) acc[i][j] = float4v{0.f, 0.f, 0.f, 0.f};

  const int r0 = tid >> 2;          // staging row 0..63
  const int c0 = (tid & 3) * 8;     // staging col chunk
  const short* ga0 = A  + (size_t)(m0 + r0) * K + c0;
  const short* ga1 = A  + (size_t)(m0 + 64 + r0) * K + c0;
  const short* gb0 = Bt + (size_t)(n0 + r0) * K + c0;
  const short* gb1 = Bt + (size_t)(n0 + 64 + r0) * K + c0;
  const short* lA0 = As + w * 512;
  const short* lA1 = As + 2048 + w * 512;
  const short* lB0 = Bs + w * 512;
  const short* lB1 = Bs + 2048 + w * 512;

  const int kTiles = K >> 5;
  for (int kt = 0; kt < kTiles; ++kt) {
    const int ko = kt * 32;
    __syncthreads();
    gl2lds16(ga0 + ko, lA0);
    gl2lds16(ga1 + ko, lA1);
    gl2lds16(gb0 + ko, lB0);
    gl2lds16(gb1 + ko, lB1);
    __syncthreads();
    short8 af[4], bfr[4];
#pragma unroll
    for (int t = 0; t < 4; ++t) {
      af[t]  = *(const short8*)&As[(wr * 64 + t * 16 + l16) * 32 + quad * 8];
      bfr[t] = *(const short8*)&Bs[(wc * 64 + t * 16 + l16) * 32 + quad * 8];
    }
#pragma unroll
    for (int i = 0; i < 4; ++i)
#pragma unroll
      for (int j = 0; j < 4; ++j)
        acc[i][j] = __builtin_amdgcn_mfma_f32_16x16x32_bf16(af[i], bfr[j], acc[i][j], 0, 0, 0);
  }

  // epilogue: C/D layout col = l16, row = quad*4 + r
#pragma unroll
  for (int i = 0; i < 4; ++i) {
#pragma unroll
    for (int j = 0; j < 4; ++j) {
#pragma unroll
      for (int r = 0; r < 4; ++r) {
        int gm = m0 + wr * 64 + i * 16 + quad * 4 + r;
        int gn = n0 + wc * 64 + j * 16 + l16;
        float v = acc[i][j][r];
        if (MODE == 0) {
          outb[(size_t)gm * ldo + gn] = f2bf(v + bias[gn]);
        } else if (MODE == 1) {
          size_t o = (size_t)gm * ldo + gn;
          resf[o] = resf[o] + v + bias[gn];
        } else if (MODE == 2) {
          float t = v + bias[gn];
          float gl = 0.5f * t * (1.0f + erff(t * 0.70710678118654752f));
          outb[(size_t)gm * ldo + gn] = f2bf(gl);
        } else {
          if (gn < Nvalid) outf[(size_t)gm * ldo + gn] = v;
        }
      }
    }
  }
}

// ---------------- GEMM-NT 64x64 tile: for N=768 GEMMs (proj / fc-proj) ----------------
// Same math/K-order as the 128 version (bitwise-identical sums), 4x the blocks:
// grid (N/64, M/64) = 384 blocks instead of 96 -> ~4.5 resident blocks/CU.
template <int MODE>
__global__ __launch_bounds__(256) void gemm_nt64(const short* __restrict__ A,
                                                 const short* __restrict__ Bt,
                                                 const float* __restrict__ bias,
                                                 float* __restrict__ resf,
                                                 short* __restrict__ outb,
                                                 int K, int ldo) {
  __shared__ __align__(16) short As[64 * 32];
  __shared__ __align__(16) short Bs[64 * 32];
  const int tid = threadIdx.x;
  const int w = tid >> 6, lane = tid & 63, quad = lane >> 4, l16 = lane & 15;
  const int wr = w & 1, wc = w >> 1;
  const int m0 = blockIdx.y * 64, n0 = blockIdx.x * 64;

  float4v acc[2][2];
#pragma unroll
  for (int i = 0; i < 2; ++i)
#pragma unroll
    for (int j = 0; j < 2; ++j) acc[i][j] = float4v{0.f, 0.f, 0.f, 0.f};

  const int r0 = tid >> 2;          // staging row 0..63
  const int c0 = (tid & 3) * 8;
  const short* ga = A  + (size_t)(m0 + r0) * K + c0;
  const short* gb = Bt + (size_t)(n0 + r0) * K + c0;
  const short* lA = As + w * 512;   // wave w stages rows [w*16, w*16+16)
  const short* lB = Bs + w * 512;

  const int kTiles = K >> 5;
  for (int kt = 0; kt < kTiles; ++kt) {
    const int ko = kt * 32;
    __syncthreads();
    gl2lds16(ga + ko, lA);
    gl2lds16(gb + ko, lB);
    __syncthreads();
    short8 af[2], bfr[2];
#pragma unroll
    for (int t = 0; t < 2; ++t) {
      af[t]  = *(const short8*)&As[(wr * 32 + t * 16 + l16) * 32 + quad * 8];
      bfr[t] = *(const short8*)&Bs[(wc * 32 + t * 16 + l16) * 32 + quad * 8];
    }
#pragma unroll
    for (int i = 0; i < 2; ++i)
#pragma unroll
      for (int j = 0; j < 2; ++j)
        acc[i][j] = __builtin_amdgcn_mfma_f32_16x16x32_bf16(af[i], bfr[j], acc[i][j], 0, 0, 0);
  }

#pragma unroll
  for (int i = 0; i < 2; ++i) {
#pragma unroll
    for (int j = 0; j < 2; ++j) {
#pragma unroll
      for (int r = 0; r < 4; ++r) {
        int gm = m0 + wr * 32 + i * 16 + quad * 4 + r;
        int gn = n0 + wc * 32 + j * 16 + l16;
        float v = acc[i][j][r];
        if (MODE == 0) {
          outb[(size_t)gm * ldo + gn] = f2bf(v + bias[gn]);
        } else if (MODE == 1) {
          size_t o = (size_t)gm * ldo + gn;
          resf[o] = resf[o] + v + bias[gn];
        } else if (MODE == 2) {
          float t = v + bias[gn];
          float gl = 0.5f * t * (1.0f + erff(t * 0.70710678118654752f));
          outb[(size_t)gm * ldo + gn] = f2bf(gl);
        }
      }
    }
  }
}

// ---------------- flash attention: qkv bf16 [B*T, H*192] -> o bf16 [B*T, C] ----------------
__global__ __launch_bounds__(256) void attn_kernel(const short* __restrict__ qkv,
                                                   short* __restrict__ o) {
  __shared__ __align__(16) short Vt[64 * 32];      // V^T tile: [d][s]
  __shared__ __align__(16) short Pl[4][16 * 32];   // per-wave P tile
  const int tid = threadIdx.x;
  const int w = tid >> 6, lane = tid & 63, quad = lane >> 4, l16 = lane & 15;
  const int b = blockIdx.z, h = blockIdx.y, q0 = blockIdx.x * 64;
  const size_t rs = 3 * CC;  // 2304
  const size_t base = (size_t)b * TT * rs + (size_t)h * 192;

  short8 qa[2];
  {
    int t = q0 + w * 16 + l16;
    const short* qp = qkv + base + (size_t)t * rs + quad * 8;
    qa[0] = *(const short8*)(qp);
    qa[1] = *(const short8*)(qp + 32);
  }
  float4v oacc[4];
#pragma unroll
  for (int i = 0; i < 4; ++i) oacc[i] = float4v{0.f, 0.f, 0.f, 0.f};
  float mrun[4] = {-1e30f, -1e30f, -1e30f, -1e30f};
  float lrun[4] = {0.f, 0.f, 0.f, 0.f};

  const int nst = q0 / 32 + 2;
  for (int st = 0; st < nst; ++st) {
    const int s0 = st * 32;
    __syncthreads();
    {   // stage V tile transposed: Vt[d][s]
      int sl = tid >> 3;          // 0..31
      int d0 = (tid & 7) * 8;
      const short* vp = qkv + base + (size_t)(s0 + sl) * rs + 128 + d0;
      short8 v8 = *(const short8*)vp;
#pragma unroll
      for (int j = 0; j < 8; ++j) Vt[(d0 + j) * 32 + sl] = v8[j];
    }
    __syncthreads();

    float4v S[2];
#pragma unroll
    for (int nt = 0; nt < 2; ++nt) {
      int s = s0 + nt * 16 + l16;
      const short* kp = qkv + base + (size_t)s * rs + 64 + quad * 8;
      short8 kb0 = *(const short8*)kp;
      short8 kb1 = *(const short8*)(kp + 32);
      float4v z = float4v{0.f, 0.f, 0.f, 0.f};
      z = __builtin_amdgcn_mfma_f32_16x16x32_bf16(qa[0], kb0, z, 0, 0, 0);
      z = __builtin_amdgcn_mfma_f32_16x16x32_bf16(qa[1], kb1, z, 0, 0, 0);
      S[nt] = z;
    }

#pragma unroll
    for (int r = 0; r < 4; ++r) {
      int trow = q0 + w * 16 + quad * 4 + r;
      float s0v = (s0 + l16      <= trow) ? S[0][r] * 0.125f : -1e30f;
      float s1v = (s0 + 16 + l16 <= trow) ? S[1][r] * 0.125f : -1e30f;
      float tm = fmaxf(s0v, s1v);
#pragma unroll
      for (int off = 1; off < 16; off <<= 1) tm = fmaxf(tm, __shfl_xor(tm, off, 64));
      float mnew = fmaxf(mrun[r], tm);
      float alpha = __expf(mrun[r] - mnew);
      mrun[r] = mnew;
      float p0 = __expf(s0v - mnew);
      float p1 = __expf(s1v - mnew);
      float rsum = p0 + p1;
#pragma unroll
      for (int off = 1; off < 16; off <<= 1) rsum += __shfl_xor(rsum, off, 64);
      lrun[r] = lrun[r] * alpha + rsum;
#pragma unroll
      for (int dc = 0; dc < 4; ++dc) oacc[dc][r] *= alpha;
      Pl[w][(quad * 4 + r) * 32 + l16]      = f2bf(p0);
      Pl[w][(quad * 4 + r) * 32 + 16 + l16] = f2bf(p1);
    }
    __syncthreads();

    short8 pa = *(const short8*)&Pl[w][l16 * 32 + quad * 8];
#pragma unroll
    for (int dc = 0; dc < 4; ++dc) {
      short8 vb = *(const short8*)&Vt[(dc * 16 + l16) * 32 + quad * 8];
      oacc[dc] = __builtin_amdgcn_mfma_f32_16x16x32_bf16(pa, vb, oacc[dc], 0, 0, 0);
    }
  }

#pragma unroll
  for (int dc = 0; dc < 4; ++dc)
#pragma unroll
    for (int r = 0; r < 4; ++r) {
      int t = q0 + w * 16 + quad * 4 + r;
      float val = oacc[dc][r] / lrun[r];
      o[(size_t)(b * TT + t) * CC + h * 64 + dc * 16 + l16] = f2bf(val);
    }
}

// ---------------- host ----------------
extern "C" void kernel_launch(void* const* d_in, const int* in_sizes, int n_in,
                              void* d_out, int out_size, void* d_ws, size_t ws_size,
                              hipStream_t stream) {
  const int*   idx   = (const int*)d_in[0];
  const float* wte   = (const float*)d_in[1];
  const float* wpe   = (const float*)d_in[2];
  const float* ln1g  = (const float*)d_in[3];
  const float* ln1b  = (const float*)d_in[4];
  const float* attnw = (const float*)d_in[5];
  const float* attnb = (const float*)d_in[6];
  const float* projw = (const float*)d_in[7];
  const float* projb = (const float*)d_in[8];
  const float* ln2g  = (const float*)d_in[9];
  const float* ln2b  = (const float*)d_in[10];
  const float* fcw   = (const float*)d_in[11];
  const float* fcb   = (const float*)d_in[12];
  const float* fpw   = (const float*)d_in[13];
  const float* fpb   = (const float*)d_in[14];
  const float* lnfg  = (const float*)d_in[15];
  const float* lnfb  = (const float*)d_in[16];
  float* out = (float*)d_out;

  char* p = (char*)d_ws;
  auto alloc = [&](size_t bytes) {
    char* r = p;
    p += (bytes + 255) & ~(size_t)255;
    return r;
  };

  const size_t SZ_ATTN = (size_t)3 * CC * CC * 2;
  const size_t SZ_PROJ = (size_t)CC * CC * 2;
  const size_t SZ_FC   = (size_t)4 * CC * CC * 2;
  const size_t SZ_FP   = (size_t)4 * CC * CC * 2;
  // batched path needs ~282 MB total; gate with margin, exact fallback otherwise
  const bool big = ws_size >= (size_t)300 * 1024 * 1024;
  const int wmul = big ? LL : 1;

  short* wt_head = (short*)alloc((size_t)VPAD * CC * 2);   // 77.3 MB
  short* wt_attn = (short*)alloc(SZ_ATTN * wmul);
  short* wt_proj = (short*)alloc(SZ_PROJ * wmul);
  short* wt_fc   = (short*)alloc(SZ_FC * wmul);
  short* wt_fp   = (short*)alloc(SZ_FP * wmul);
  float* x       = (float*)alloc((size_t)BT * CC * 4);     // f32 residual stream
  short* hbuf    = (short*)alloc((size_t)BT * CC * 2);     // LN output (bf16)
  short* obuf    = (short*)alloc((size_t)BT * CC * 2);     // attention output (bf16)
  short* qkvb    = (short*)alloc((size_t)BT * 3 * CC * 2); // qkv (bf16)
  short* fcout   = (short*)alloc((size_t)BT * 4 * CC * 2); // gelu(fc) (bf16)

  cast_pad_kernel<<<dim3(((long)VPAD * CC) / 1024), 256, 0, stream>>>(
      wte, wt_head, (long)VV * CC, (long)VPAD * CC);
  embed_kernel<<<dim3(BT), 256, 0, stream>>>(idx, wte, wpe, x);

  if (big) {
    // all 12 layers' weight transposes in 4 launches (z = layer)
    transpose_cast_kernel<<<dim3(2304 / 32, 768 / 32, LL), 256, 0, stream>>>(
        attnw, wt_attn, CC, 3 * CC, (long)CC * 3 * CC, (long)3 * CC * CC);
    transpose_cast_kernel<<<dim3(768 / 32, 768 / 32, LL), 256, 0, stream>>>(
        projw, wt_proj, CC, CC, (long)CC * CC, (long)CC * CC);
    transpose_cast_kernel<<<dim3(3072 / 32, 768 / 32, LL), 256, 0, stream>>>(
        fcw, wt_fc, CC, 4 * CC, (long)CC * 4 * CC, (long)4 * CC * CC);
    transpose_cast_kernel<<<dim3(768 / 32, 3072 / 32, LL), 256, 0, stream>>>(
        fpw, wt_fp, 4 * CC, CC, (long)4 * CC * CC, (long)4 * CC * CC);
  }

  for (int l = 0; l < LL; ++l) {
    const short* wa = wt_attn + (big ? (size_t)l * 3 * CC * CC : 0);
    const short* wp = wt_proj + (big ? (size_t)l * CC * CC : 0);
    const short* wf = wt_fc   + (big ? (size_t)l * 4 * CC * CC : 0);
    const short* wq = wt_fp   + (big ? (size_t)l * 4 * CC * CC : 0);

    if (!big) {
      transpose_cast_kernel<<<dim3(2304 / 32, 768 / 32, 1), 256, 0, stream>>>(
          attnw + (size_t)l * CC * 3 * CC, wt_attn, CC, 3 * CC, 0, 0);
      transpose_cast_kernel<<<dim3(768 / 32, 768 / 32, 1), 256, 0, stream>>>(
          projw + (size_t)l * CC * CC, wt_proj, CC, CC, 0, 0);
      transpose_cast_kernel<<<dim3(3072 / 32, 768 / 32, 1), 256, 0, stream>>>(
          fcw + (size_t)l * CC * 4 * CC, wt_fc, CC, 4 * CC, 0, 0);
      transpose_cast_kernel<<<dim3(768 / 32, 3072 / 32, 1), 256, 0, stream>>>(
          fpw + (size_t)l * 4 * CC * CC, wt_fp, 4 * CC, CC, 0, 0);
    }

    ln_kernel<<<dim3(BT), 256, 0, stream>>>(x, ln1g + l * CC, ln1b + l * CC, hbuf);
    gemm_nt<0><<<dim3(18, 16), 256, 0, stream>>>(
        hbuf, wa, attnb + (size_t)l * 3 * CC, nullptr, qkvb, nullptr, CC, 3 * CC, 3 * CC);
    attn_kernel<<<dim3(TT / 64, HH, 2), 256, 0, stream>>>(qkvb, obuf);
    gemm_nt64<1><<<dim3(12, 32), 256, 0, stream>>>(
        obuf, wp, projb + (size_t)l * CC, x, nullptr, CC, CC);
    ln_kernel<<<dim3(BT), 256, 0, stream>>>(x, ln2g + l * CC, ln2b + l * CC, hbuf);
    gemm_nt<2><<<dim3(24, 16), 256, 0, stream>>>(
        hbuf, wf, fcb + (size_t)l * 4 * CC, nullptr, fcout, nullptr, CC, 4 * CC, 4 * CC);
    gemm_nt64<1><<<dim3(12, 32), 256, 0, stream>>>(
        fcout, wq, fpb + (size_t)l * CC, x, nullptr, 4 * CC, CC);
  }

  ln_kernel<<<dim3(BT), 256, 0, stream>>>(x, lnfg, lnfb, hbuf);
  // head: 1-D swizzled launch (6288 blocks, %8==0 -> bijective XCD chunks)
  gemm_nt<3, 1><<<dim3((VPAD / 128) * 16), 256, 0, stream>>>(
      hbuf, wt_head, nullptr, nullptr, nullptr, out, CC, VV, VV);
}